// Round 13
// baseline (559.750 us; speedup 1.0000x reference)
//
#include <hip/hip_runtime.h>
#include <math.h>

#define NNODES 50000
#define NEDGES 800000
#define AVGDLOG 2.833f
#define EPSF 1e-5f
#define TPB_E 8
#define NSCAN 49  // ceil(50000/1024)

typedef __attribute__((ext_vector_type(8))) short short8;
typedef __attribute__((ext_vector_type(4))) float f32x4;

__device__ __forceinline__ unsigned f2bf(float x) {
    unsigned u = __float_as_uint(x);
    return (u + 0x7FFFu + ((u >> 16) & 1u)) >> 16;
}
__device__ __forceinline__ float bf2f(unsigned lo16) {
    return __uint_as_float(lo16 << 16);
}
__device__ __forceinline__ void up8(uint4 v, float* f) {
    f[0] = bf2f(v.x & 0xffffu); f[1] = bf2f(v.x >> 16);
    f[2] = bf2f(v.y & 0xffffu); f[3] = bf2f(v.y >> 16);
    f[4] = bf2f(v.z & 0xffffu); f[5] = bf2f(v.z >> 16);
    f[6] = bf2f(v.w & 0xffffu); f[7] = bf2f(v.w >> 16);
}
__device__ __forceinline__ uint4 pk8(const float* f) {
    uint4 v;
    v.x = f2bf(f[0]) | (f2bf(f[1]) << 16);
    v.y = f2bf(f[2]) | (f2bf(f[3]) << 16);
    v.z = f2bf(f[4]) | (f2bf(f[5]) << 16);
    v.w = f2bf(f[6]) | (f2bf(f[7]) << 16);
    return v;
}

// ---------------- CSR ----------------
__global__ void k_zero(unsigned* __restrict__ deg) {
    int i = blockIdx.x * 256 + threadIdx.x;
    if (i < NNODES) deg[i] = 0u;
}
__global__ void k_count(const int* __restrict__ dst, unsigned* __restrict__ deg) {
    int i = blockIdx.x * 256 + threadIdx.x;
    if (i < NEDGES) atomicAdd(&deg[dst[i]], 1u);
}
__global__ void k_scanA(const unsigned* __restrict__ deg, int* __restrict__ bsum) {
    __shared__ int wsum[4];
    const int t = threadIdx.x, b = blockIdx.x;
    int i = b * 1024 + t * 4;
    int s = 0;
    if (i + 4 <= NNODES) {
        int4 v = *(const int4*)(deg + i);
        s = v.x + v.y + v.z + v.w;
    } else {
        for (int k = 0; k < 4; ++k) if (i + k < NNODES) s += (int)deg[i + k];
    }
#pragma unroll
    for (int off = 1; off < 64; off <<= 1) s += __shfl_xor(s, off);
    if ((t & 63) == 0) wsum[t >> 6] = s;
    __syncthreads();
    if (t == 0) bsum[b] = wsum[0] + wsum[1] + wsum[2] + wsum[3];
}
__global__ void k_scanB(const int* __restrict__ bsum, int* __restrict__ boff,
                        int* __restrict__ basep) {
    if (threadIdx.x == 0) {
        int run = 0;
        for (int b = 0; b < NSCAN; ++b) { boff[b] = run; run += bsum[b]; }
        basep[NNODES] = run;
    }
}
__global__ void k_scanC(const unsigned* __restrict__ deg, const int* __restrict__ boff,
                        int* __restrict__ basep, int* __restrict__ cursor) {
    __shared__ int ps[256];
    const int t = threadIdx.x, b = blockIdx.x;
    int i = b * 1024 + t * 4;
    int v0 = 0, v1 = 0, v2 = 0, v3 = 0;
    if (i + 4 <= NNODES) {
        int4 v = *(const int4*)(deg + i);
        v0 = v.x; v1 = v.y; v2 = v.z; v3 = v.w;
    } else {
        if (i < NNODES) v0 = (int)deg[i];
        if (i + 1 < NNODES) v1 = (int)deg[i + 1];
        if (i + 2 < NNODES) v2 = (int)deg[i + 2];
        if (i + 3 < NNODES) v3 = (int)deg[i + 3];
    }
    int ts = v0 + v1 + v2 + v3;
    ps[t] = ts;
    __syncthreads();
    for (int off = 1; off < 256; off <<= 1) {
        int x = (t >= off) ? ps[t - off] : 0;
        __syncthreads();
        ps[t] += x;
        __syncthreads();
    }
    int excl = ps[t] - ts + boff[b];
    if (i < NNODES) { basep[i] = excl; cursor[i] = excl; }
    if (i + 1 < NNODES) { basep[i + 1] = excl + v0; cursor[i + 1] = excl + v0; }
    if (i + 2 < NNODES) { basep[i + 2] = excl + v0 + v1; cursor[i + 2] = excl + v0 + v1; }
    if (i + 3 < NNODES) { basep[i + 3] = excl + v0 + v1 + v2; cursor[i + 3] = excl + v0 + v1 + v2; }
}
__global__ void k_scatter(const int* __restrict__ dst, int* __restrict__ cursor,
                          int* __restrict__ slotArr) {
    int i = blockIdx.x * 256 + threadIdx.x;
    if (i < NEDGES) {
        int d = dst[i];
        slotArr[i] = atomicAdd(&cursor[d], 1);
    }
}

// ---------------- weight prep ----------------
__global__ void k_convW(const float* __restrict__ Wpre, const float* __restrict__ Wpost,
                        unsigned short* __restrict__ W3t, unsigned short* __restrict__ W12t,
                        unsigned short* __restrict__ Bhat) {
    int i = blockIdx.x * 256 + threadIdx.x;
    if (i < 128 * 128) {
        int n = i & 127, k = i >> 7;
        W3t[n * 128 + k] = (unsigned short)f2bf(Wpre[(256 + k) * 128 + n]);
    }
    if (i < 256 * 128) {
        int n = i >> 7, k = i & 127;
        float v = (n < 128) ? Wpre[k * 128 + n] : Wpre[(128 + k) * 128 + (n - 128)];
        W12t[n * 128 + k] = (unsigned short)f2bf(v);
    }
    if (i < 640 * 384) {
        int kc = i / (384 * 32);
        int rem = i % (384 * 32);
        int n = rem >> 5, kk = rem & 31;
        int k = kc * 32 + kk, c = n & 127, g = n >> 7;
        float v;
        if (g == 0) v = Wpost[k * 128 + c];
        else if (g == 1) v = (k < 128) ? 0.f : Wpost[(512 + k) * 128 + c];
        else v = (k < 128) ? 0.f : Wpost[(1024 + k) * 128 + c];
        Bhat[i] = (unsigned short)f2bf(v);
    }
}

// ---------------- P12 = h @ [W1|W2] (MFMA); also emits bf16(h) into Abuf[:,0:128] ----------------
__global__ __launch_bounds__(256) void k_p12(const float* __restrict__ h,
                                             const unsigned short* __restrict__ W12t,
                                             unsigned short* __restrict__ P1,
                                             unsigned short* __restrict__ P2,
                                             unsigned short* __restrict__ Abuf) {
    __shared__ __align__(16) unsigned short As[64 * 128];
    __shared__ __align__(16) unsigned short Bs[256 * 128];
    const int t = threadIdx.x;
    const size_t row0 = (size_t)blockIdx.x * 64;
#pragma unroll
    for (int j = 0; j < 16; ++j) {
        int idx = t + 256 * j;
        int n = idx >> 4, q = idx & 15;
        uint4 wv = *(const uint4*)(W12t + n * 128 + q * 8);
        *(uint4*)((char*)Bs + n * 256 + ((q * 16) ^ ((n & 7) << 4))) = wv;
    }
#pragma unroll
    for (int j = 0; j < 8; ++j) {
        int idx = t + 256 * j;
        int r = idx >> 5, q = idx & 31;
        size_t row = row0 + r;
        uint2 p = {0u, 0u};
        if (row < NNODES) {
            float4 z = ((const float4*)h)[row * 32 + q];
            p.x = f2bf(z.x) | (f2bf(z.y) << 16);
            p.y = f2bf(z.z) | (f2bf(z.w) << 16);
            *(uint2*)(Abuf + row * 640 + q * 4) = p;
        }
        *(uint2*)((char*)As + r * 256 + ((q * 8) ^ ((r & 7) << 4))) = p;
    }
    __syncthreads();
    const int w = t >> 6, lane = t & 63, lrow = lane & 15, lkb = lane >> 4;
    f32x4 acc[16];
#pragma unroll
    for (int i = 0; i < 16; ++i) acc[i] = (f32x4){0.f, 0.f, 0.f, 0.f};
    const char* Abase = (const char*)As + (w * 16 + lrow) * 256;
    const unsigned aswz = (unsigned)(((w * 16 + lrow) & 7) << 4);
#pragma unroll
    for (int kk = 0; kk < 4; ++kk) {
        int kbyte = (kk * 32 + lkb * 8) * 2;
        short8 af = *(const short8*)(Abase + (kbyte ^ aswz));
#pragma unroll
        for (int nt = 0; nt < 16; ++nt) {
            int n = nt * 16 + lrow;
            short8 bf = *(const short8*)((const char*)Bs + n * 256 + (kbyte ^ ((n & 7) << 4)));
            acc[nt] = __builtin_amdgcn_mfma_f32_16x16x32_bf16(af, bf, acc[nt], 0, 0, 0);
        }
    }
#pragma unroll
    for (int half = 0; half < 2; ++half) {
        __syncthreads();
#pragma unroll
        for (int nt = 0; nt < 8; ++nt) {
            int c = nt * 16 + lrow;
#pragma unroll
            for (int i = 0; i < 4; ++i) {
                int lr = w * 16 + lkb * 4 + i;
                *(unsigned short*)((char*)As + lr * 256 + ((c * 2) ^ ((lr & 7) << 4))) =
                    (unsigned short)f2bf(acc[half * 8 + nt][i]);
            }
        }
        __syncthreads();
        unsigned short* dstP = half ? P2 : P1;
#pragma unroll
        for (int j = 0; j < 4; ++j) {
            int idx = t + 256 * j;
            int r = idx >> 4, q = idx & 15;
            size_t row = row0 + r;
            if (row < NNODES) {
                uint4 v = *(const uint4*)((const char*)As + r * 256 + ((q * 16) ^ ((r & 7) << 4)));
                *(uint4*)(dstP + row * 128 + q * 8) = v;
            }
        }
    }
}

// ---------------- G[slotArr[eid]] = bf16(e[eid]@W3 + bpre + P1[src[eid]]) ----------------
// Single As buffer (52 KB LDS -> 3 blocks/CU); reg pipeline rbuf[2] stages 2 tiles ahead.
__global__ __launch_bounds__(256) void k_gemm_e(const float* __restrict__ e,
                                                const int* __restrict__ src,
                                                const int* __restrict__ slotArr,
                                                const unsigned short* __restrict__ W3t,
                                                const float* __restrict__ bpre,
                                                const unsigned short* __restrict__ P1,
                                                unsigned short* __restrict__ G) {
    __shared__ __align__(16) unsigned short Bs[128 * 128];   // persistent W3 (32 KB)
    __shared__ __align__(16) unsigned short As[64 * 128];    // single A buffer (16 KB)
    __shared__ int Ssl[TPB_E * 64];
    __shared__ int Ssr[TPB_E * 64];
    const int t = threadIdx.x;
    const int tile0 = blockIdx.x * TPB_E;
    const int ntiles = min(TPB_E, 12500 - tile0);

    for (int j = t; j < ntiles * 64; j += 256) {
        int row = tile0 * 64 + j;
        Ssl[j] = slotArr[row];
        Ssr[j] = src[row];
    }

    const int q = t & 31, r5 = t >> 5;
    float4 rbuf[2][8];
    auto loadE = [&](int ti, float4* ra) {
        const float4* ep = (const float4*)e + (size_t)(tile0 + ti) * 2048;
#pragma unroll
        for (int j = 0; j < 8; ++j)
            ra[j] = ep[(r5 + 8 * j) * 32 + q];   // fully linear, coalesced
    };
    auto storeA = [&](const float4* ra) {
#pragma unroll
        for (int j = 0; j < 8; ++j) {
            int r = r5 + 8 * j;
            uint2 pv;
            pv.x = f2bf(ra[j].x) | (f2bf(ra[j].y) << 16);
            pv.y = f2bf(ra[j].z) | (f2bf(ra[j].w) << 16);
            *(uint2*)((char*)As + r * 256 + ((q * 8) ^ ((r & 7) << 4))) = pv;
        }
    };

    loadE(0, rbuf[0]);
#pragma unroll
    for (int j = 0; j < 8; ++j) {
        int idx = t + 256 * j;
        int n = idx >> 4, qq = idx & 15;
        uint4 wv = *(const uint4*)(W3t + n * 128 + qq * 8);
        *(uint4*)((char*)Bs + n * 256 + ((qq * 16) ^ ((n & 7) << 4))) = wv;
    }
    if (ntiles > 1) loadE(1, rbuf[1]);

    const int w = t >> 6, lane = t & 63, lrow = lane & 15, lkb = lane >> 4;
    float bpf[8];
#pragma unroll
    for (int nt = 0; nt < 8; ++nt) bpf[nt] = bpre[nt * 16 + lrow];

    for (int ti = 0; ti < ntiles; ++ti) {
        storeA(rbuf[ti & 1]);                     // stage tile ti (prev flush done per bar D)
        if (ti + 2 < ntiles) loadE(ti + 2, rbuf[ti & 1]);  // refill freed reg slot
        __syncthreads();   // (A) staged As visible (also covers Bs/meta on first iter)
        f32x4 acc[8];
#pragma unroll
        for (int i = 0; i < 8; ++i) acc[i] = (f32x4){0.f, 0.f, 0.f, 0.f};
        const char* Ab = (const char*)As + (w * 16 + lrow) * 256;
        const unsigned aswz = (unsigned)(((w * 16 + lrow) & 7) << 4);
#pragma unroll
        for (int kk = 0; kk < 4; ++kk) {
            int kbyte = (kk * 32 + lkb * 8) * 2;
            short8 af = *(const short8*)(Ab + (kbyte ^ aswz));
#pragma unroll
            for (int nt = 0; nt < 8; ++nt) {
                int n = nt * 16 + lrow;
                short8 bf = *(const short8*)((const char*)Bs + n * 256 + (kbyte ^ ((n & 7) << 4)));
                acc[nt] = __builtin_amdgcn_mfma_f32_16x16x32_bf16(af, bf, acc[nt], 0, 0, 0);
            }
        }
        __syncthreads();   // (B) MFMA reads of As done
#pragma unroll
        for (int nt = 0; nt < 8; ++nt) {
            int cc = nt * 16 + lrow;
#pragma unroll
            for (int i = 0; i < 4; ++i) {
                int lr = w * 16 + lkb * 4 + i;
                *(unsigned short*)((char*)As + lr * 256 + ((cc * 2) ^ ((lr & 7) << 4))) =
                    (unsigned short)f2bf(acc[nt][i] + bpf[nt]);
            }
        }
        __syncthreads();   // (C) scatter visible
        // flush: add P1 row, scatter-write to G[slot]
#pragma unroll
        for (int j = 0; j < 4; ++j) {
            int idx = t + 256 * j;
            int r = idx >> 4, qq = idx & 15;
            uint4 v = *(const uint4*)((const char*)As + r * 256 + ((qq * 16) ^ ((r & 7) << 4)));
            uint4 pv = *(const uint4*)(P1 + (size_t)Ssr[ti * 64 + r] * 128 + qq * 8);
            float gf[8], pf[8];
            up8(v, gf); up8(pv, pf);
#pragma unroll
            for (int k = 0; k < 8; ++k) gf[k] += pf[k];
            *(uint4*)(G + (size_t)Ssl[ti * 64 + r] * 128 + qq * 8) = pk8(gf);
        }
        __syncthreads();   // (D) flush reads of As done before next storeA
    }
}

// ---------------- segmented reduce: stream G (sorted order); P2 shift at flush ----------------
__global__ __launch_bounds__(256) void k_reduce(const unsigned short* __restrict__ G,
                                                const unsigned short* __restrict__ P2,
                                                const int* __restrict__ basep,
                                                unsigned short* __restrict__ Abuf) {
    const int t = threadIdx.x;
    const int n = blockIdx.x * 4 + (t >> 6);
    const int lane = t & 63, lq = lane >> 4, lc = lane & 15;
    int b0 = basep[n], b1 = basep[n + 1];
    int dg = b1 - b0;
    float s[8], q2[8], mx[8], mn[8];
#pragma unroll
    for (int j = 0; j < 8; ++j) { s[j] = 0.f; q2[j] = 0.f; mx[j] = -3.4e38f; mn[j] = 3.4e38f; }
    for (int sl = b0 + lq; sl < b1; sl += 4) {
        float gf[8];
        up8(*(const uint4*)(G + (size_t)sl * 128 + lc * 8), gf);
#pragma unroll
        for (int j = 0; j < 8; ++j) {
            float m = gf[j];
            s[j] += m; q2[j] = fmaf(m, m, q2[j]);
            mx[j] = fmaxf(mx[j], m); mn[j] = fminf(mn[j], m);
        }
    }
#pragma unroll
    for (int off = 16; off <= 32; off <<= 1) {
#pragma unroll
        for (int j = 0; j < 8; ++j) {
            s[j] += __shfl_xor(s[j], off);
            q2[j] += __shfl_xor(q2[j], off);
            mx[j] = fmaxf(mx[j], __shfl_xor(mx[j], off));
            mn[j] = fminf(mn[j], __shfl_xor(mn[j], off));
        }
    }
    if (lane < 16) {
        float mean[8], sd[8], X[8], N[8];
        if (dg > 0) {
            float ds = (float)dg;
            float p2f[8];
            up8(*(const uint4*)(P2 + (size_t)n * 128 + lc * 8), p2f);
#pragma unroll
            for (int j = 0; j < 8; ++j) {
                float mg = s[j] / ds;
                float v = fmaxf(q2[j] / ds - mg * mg, 0.f);
                sd[j] = sqrtf(v + EPSF);
                mean[j] = mg + p2f[j];
                X[j] = mx[j] + p2f[j];
                N[j] = mn[j] + p2f[j];
            }
        } else {
#pragma unroll
            for (int j = 0; j < 8; ++j) { mean[j] = 0.f; sd[j] = 0.f; X[j] = 0.f; N[j] = 0.f; }
        }
        unsigned short* row = Abuf + (size_t)n * 640 + 128 + lc * 8;
        *(uint4*)(row) = pk8(mean);
        *(uint4*)(row + 128) = pk8(X);
        *(uint4*)(row + 256) = pk8(N);
        *(uint4*)(row + 384) = pk8(sd);
    }
}

// ---------------- out = C0 + amp*C1 + att*C2 + b, *snorm ; C = A[50000,640] @ Bhat[640,384] ----------------
__global__ __launch_bounds__(512) void k_gemm_post(const unsigned short* __restrict__ Abuf,
                                                   const unsigned short* __restrict__ Bhat,
                                                   const float* __restrict__ bpost,
                                                   const float* __restrict__ snorm,
                                                   const int* __restrict__ basep,
                                                   float* __restrict__ out) {
    __shared__ __align__(16) unsigned short As[2][128 * 32];
    __shared__ __align__(16) unsigned short Bs[2][384 * 32];
    __shared__ float sAmp[128], sAtt[128], sSn[128], sBp[128];
    const int t = threadIdx.x;
    const size_t row0 = (size_t)blockIdx.x * 128;
    if (t < 128) {
        size_t nn = row0 + t;
        float a = 0.f, b = 0.f, sn = 0.f;
        if (nn < NNODES) {
            int dgi = basep[nn + 1] - basep[nn];
            a = logf((float)dgi + 1.f) * (1.f / AVGDLOG);
            b = AVGDLOG / logf(fmaxf((float)dgi, 1.f) + 1.f);
            sn = snorm[nn];
        }
        sAmp[t] = a; sAtt[t] = b; sSn[t] = sn; sBp[t] = bpost[t];
    }
    const int arow = t >> 2, ak4 = t & 3;
    auto loadA = [&](int kc, uint4& ra) {
        ra = (uint4){0u, 0u, 0u, 0u};
        if (row0 + arow < NNODES)
            ra = *(const uint4*)(Abuf + (row0 + arow) * 640 + kc * 32 + ak4 * 8);
    };
    auto loadB = [&](int kc, uint4* rb) {
#pragma unroll
        for (int j = 0; j < 3; ++j) {
            int idx = t + 512 * j;
            int n = idx >> 2, k4 = idx & 3;
            rb[j] = *(const uint4*)(Bhat + ((size_t)kc * 384 + n) * 32 + k4 * 8);
        }
    };
    auto storeLDS = [&](int buf, const uint4& ra, const uint4* rb) {
        *(uint4*)((char*)As[buf] + arow * 64 + ((ak4 * 16) ^ ((arow & 3) << 4))) = ra;
#pragma unroll
        for (int j = 0; j < 3; ++j) {
            int idx = t + 512 * j;
            int n = idx >> 2, k4 = idx & 3;
            *(uint4*)((char*)Bs[buf] + n * 64 + ((k4 * 16) ^ ((n & 3) << 4))) = rb[j];
        }
    };
    const int w = t >> 6, wm = w & 1, wn = w >> 1;
    const int lane = t & 63, lrow = lane & 15, lkb = lane >> 4;
    f32x4 acc[4][6];
#pragma unroll
    for (int a = 0; a < 4; ++a)
#pragma unroll
        for (int b = 0; b < 6; ++b) acc[a][b] = (f32x4){0.f, 0.f, 0.f, 0.f};

    uint4 ra, rb[3];
    loadA(0, ra); loadB(0, rb);
    storeLDS(0, ra, rb);
    int cur = 0;
    for (int kc = 0; kc < 20; ++kc) {
        if (kc < 19) { loadA(kc + 1, ra); loadB(kc + 1, rb); }
        __syncthreads();
        short8 af[4];
#pragma unroll
        for (int mi = 0; mi < 4; ++mi) {
            int r = wm * 64 + mi * 16 + lrow;
            af[mi] = *(const short8*)((const char*)As[cur] + r * 64 + ((lkb * 16) ^ ((r & 3) << 4)));
        }
        short8 bfv[6];
#pragma unroll
        for (int g = 0; g < 3; ++g)
#pragma unroll
            for (int j = 0; j < 2; ++j) {
                int nn = g * 128 + wn * 32 + j * 16 + lrow;
                bfv[g * 2 + j] = *(const short8*)((const char*)Bs[cur] + nn * 64 + ((lkb * 16) ^ ((nn & 3) << 4)));
            }
#pragma unroll
        for (int mi = 0; mi < 4; ++mi)
#pragma unroll
            for (int f = 0; f < 6; ++f)
                acc[mi][f] = __builtin_amdgcn_mfma_f32_16x16x32_bf16(af[mi], bfv[f], acc[mi][f], 0, 0, 0);
        if (kc < 19) storeLDS(cur ^ 1, ra, rb);
        cur ^= 1;
    }
#pragma unroll
    for (int mi = 0; mi < 4; ++mi)
#pragma unroll
        for (int j = 0; j < 2; ++j)
#pragma unroll
            for (int i = 0; i < 4; ++i) {
                int r = wm * 64 + mi * 16 + lkb * 4 + i;
                size_t grow = row0 + r;
                if (grow < NNODES) {
                    int c = wn * 32 + j * 16 + lrow;
                    float v = acc[mi][j][i] + sAmp[r] * acc[mi][2 + j][i] + sAtt[r] * acc[mi][4 + j][i] + sBp[c];
                    out[grow * 128 + c] = v * sSn[r];
                }
            }
}

extern "C" void kernel_launch(void* const* d_in, const int* in_sizes, int n_in,
                              void* d_out, int out_size, void* d_ws, size_t ws_size,
                              hipStream_t stream) {
    const float* h = (const float*)d_in[0];
    const float* e = (const float*)d_in[1];
    const float* snorm = (const float*)d_in[2];
    const int* src = (const int*)d_in[3];
    const int* dst = (const int*)d_in[4];
    const float* Wpre = (const float*)d_in[5];
    const float* bpre = (const float*)d_in[6];
    const float* Wpost = (const float*)d_in[7];
    const float* bpost = (const float*)d_in[8];
    float* out = (float*)d_out;

    char* p = (char*)d_ws;
    auto alloc = [&](size_t bytes) { char* r = p; p += (bytes + 255) & ~(size_t)255; return r; };
    unsigned short* P1 = (unsigned short*)alloc((size_t)NNODES * 128 * 2);
    unsigned short* P2 = (unsigned short*)alloc((size_t)NNODES * 128 * 2);
    unsigned short* Abuf = (unsigned short*)alloc((size_t)NNODES * 640 * 2);
    unsigned short* G = (unsigned short*)alloc((size_t)NEDGES * 128 * 2);
    unsigned short* W3t = (unsigned short*)alloc(128 * 128 * 2);
    unsigned short* W12t = (unsigned short*)alloc(256 * 128 * 2);
    unsigned short* Bhat = (unsigned short*)alloc((size_t)640 * 384 * 2);
    unsigned* deg = (unsigned*)alloc((size_t)NNODES * 4);
    int* basep = (int*)alloc((size_t)(NNODES + 1) * 4);
    int* cursor = (int*)alloc((size_t)NNODES * 4);
    int* slotArr = (int*)alloc((size_t)NEDGES * 4);
    int* bsum = (int*)alloc((size_t)NSCAN * 4);
    int* boff = (int*)alloc((size_t)NSCAN * 4);

    k_zero<<<(NNODES + 255) / 256, 256, 0, stream>>>(deg);
    k_count<<<(NEDGES + 255) / 256, 256, 0, stream>>>(dst, deg);
    k_scanA<<<NSCAN, 256, 0, stream>>>(deg, bsum);
    k_scanB<<<1, 64, 0, stream>>>(bsum, boff, basep);
    k_scanC<<<NSCAN, 256, 0, stream>>>(deg, boff, basep, cursor);
    k_scatter<<<(NEDGES + 255) / 256, 256, 0, stream>>>(dst, cursor, slotArr);
    k_convW<<<(640 * 384 + 255) / 256, 256, 0, stream>>>(Wpre, Wpost, W3t, W12t, Bhat);
    k_p12<<<(NNODES + 63) / 64, 256, 0, stream>>>(h, W12t, P1, P2, Abuf);
    k_gemm_e<<<(12500 + TPB_E - 1) / TPB_E, 256, 0, stream>>>(e, src, slotArr, W3t, bpre, P1, G);
    k_reduce<<<NNODES / 4, 256, 0, stream>>>(G, P2, basep, Abuf);
    k_gemm_post<<<(NNODES + 127) / 128, 512, 0, stream>>>(Abuf, Bhat, bpost, snorm, basep, out);
}

// Round 14
// 484.772 us; speedup vs baseline: 1.1547x; 1.1547x over previous
//
#include <hip/hip_runtime.h>
#include <math.h>

#define NNODES 50000
#define NEDGES 800000
#define AVGDLOG 2.833f
#define EPSF 1e-5f
#define TPB_E 8
#define NSCAN 49  // ceil(50000/1024)

typedef __attribute__((ext_vector_type(8))) short short8;
typedef __attribute__((ext_vector_type(4))) float f32x4;

__device__ __forceinline__ unsigned f2bf(float x) {
    unsigned u = __float_as_uint(x);
    return (u + 0x7FFFu + ((u >> 16) & 1u)) >> 16;
}
__device__ __forceinline__ float bf2f(unsigned lo16) {
    return __uint_as_float(lo16 << 16);
}
__device__ __forceinline__ void up8(uint4 v, float* f) {
    f[0] = bf2f(v.x & 0xffffu); f[1] = bf2f(v.x >> 16);
    f[2] = bf2f(v.y & 0xffffu); f[3] = bf2f(v.y >> 16);
    f[4] = bf2f(v.z & 0xffffu); f[5] = bf2f(v.z >> 16);
    f[6] = bf2f(v.w & 0xffffu); f[7] = bf2f(v.w >> 16);
}
__device__ __forceinline__ uint4 pk8(const float* f) {
    uint4 v;
    v.x = f2bf(f[0]) | (f2bf(f[1]) << 16);
    v.y = f2bf(f[2]) | (f2bf(f[3]) << 16);
    v.z = f2bf(f[4]) | (f2bf(f[5]) << 16);
    v.w = f2bf(f[6]) | (f2bf(f[7]) << 16);
    return v;
}

// ---------------- CSR ----------------
__global__ void k_zero(unsigned* __restrict__ deg) {
    int i = blockIdx.x * 256 + threadIdx.x;
    if (i < NNODES) deg[i] = 0u;
}
__global__ void k_count(const int* __restrict__ dst, unsigned* __restrict__ deg) {
    int i = blockIdx.x * 256 + threadIdx.x;
    if (i < NEDGES) atomicAdd(&deg[dst[i]], 1u);
}
__global__ void k_scanA(const unsigned* __restrict__ deg, int* __restrict__ bsum) {
    __shared__ int wsum[4];
    const int t = threadIdx.x, b = blockIdx.x;
    int i = b * 1024 + t * 4;
    int s = 0;
    if (i + 4 <= NNODES) {
        int4 v = *(const int4*)(deg + i);
        s = v.x + v.y + v.z + v.w;
    } else {
        for (int k = 0; k < 4; ++k) if (i + k < NNODES) s += (int)deg[i + k];
    }
#pragma unroll
    for (int off = 1; off < 64; off <<= 1) s += __shfl_xor(s, off);
    if ((t & 63) == 0) wsum[t >> 6] = s;
    __syncthreads();
    if (t == 0) bsum[b] = wsum[0] + wsum[1] + wsum[2] + wsum[3];
}
__global__ void k_scanB(const int* __restrict__ bsum, int* __restrict__ boff,
                        int* __restrict__ basep) {
    if (threadIdx.x == 0) {
        int run = 0;
        for (int b = 0; b < NSCAN; ++b) { boff[b] = run; run += bsum[b]; }
        basep[NNODES] = run;
    }
}
__global__ void k_scanC(const unsigned* __restrict__ deg, const int* __restrict__ boff,
                        int* __restrict__ basep, int* __restrict__ cursor) {
    __shared__ int ps[256];
    const int t = threadIdx.x, b = blockIdx.x;
    int i = b * 1024 + t * 4;
    int v0 = 0, v1 = 0, v2 = 0, v3 = 0;
    if (i + 4 <= NNODES) {
        int4 v = *(const int4*)(deg + i);
        v0 = v.x; v1 = v.y; v2 = v.z; v3 = v.w;
    } else {
        if (i < NNODES) v0 = (int)deg[i];
        if (i + 1 < NNODES) v1 = (int)deg[i + 1];
        if (i + 2 < NNODES) v2 = (int)deg[i + 2];
        if (i + 3 < NNODES) v3 = (int)deg[i + 3];
    }
    int ts = v0 + v1 + v2 + v3;
    ps[t] = ts;
    __syncthreads();
    for (int off = 1; off < 256; off <<= 1) {
        int x = (t >= off) ? ps[t - off] : 0;
        __syncthreads();
        ps[t] += x;
        __syncthreads();
    }
    int excl = ps[t] - ts + boff[b];
    if (i < NNODES) { basep[i] = excl; cursor[i] = excl; }
    if (i + 1 < NNODES) { basep[i + 1] = excl + v0; cursor[i + 1] = excl + v0; }
    if (i + 2 < NNODES) { basep[i + 2] = excl + v0 + v1; cursor[i + 2] = excl + v0 + v1; }
    if (i + 3 < NNODES) { basep[i + 3] = excl + v0 + v1 + v2; cursor[i + 3] = excl + v0 + v1 + v2; }
}
__global__ void k_scatter(const int* __restrict__ dst, int* __restrict__ cursor,
                          int* __restrict__ slotArr) {
    int i = blockIdx.x * 256 + threadIdx.x;
    if (i < NEDGES) {
        int d = dst[i];
        slotArr[i] = atomicAdd(&cursor[d], 1);
    }
}

// ---------------- weight prep ----------------
__global__ void k_convW(const float* __restrict__ Wpre, const float* __restrict__ Wpost,
                        unsigned short* __restrict__ W3t, unsigned short* __restrict__ W12t,
                        unsigned short* __restrict__ Bhat) {
    int i = blockIdx.x * 256 + threadIdx.x;
    if (i < 128 * 128) {
        int n = i & 127, k = i >> 7;
        W3t[n * 128 + k] = (unsigned short)f2bf(Wpre[(256 + k) * 128 + n]);
    }
    if (i < 256 * 128) {
        int n = i >> 7, k = i & 127;
        float v = (n < 128) ? Wpre[k * 128 + n] : Wpre[(128 + k) * 128 + (n - 128)];
        W12t[n * 128 + k] = (unsigned short)f2bf(v);
    }
    if (i < 640 * 384) {
        int kc = i / (384 * 32);
        int rem = i % (384 * 32);
        int n = rem >> 5, kk = rem & 31;
        int k = kc * 32 + kk, c = n & 127, g = n >> 7;
        float v;
        if (g == 0) v = Wpost[k * 128 + c];
        else if (g == 1) v = (k < 128) ? 0.f : Wpost[(512 + k) * 128 + c];
        else v = (k < 128) ? 0.f : Wpost[(1024 + k) * 128 + c];
        Bhat[i] = (unsigned short)f2bf(v);
    }
}

// ---------------- P12 = h @ [W1|W2] (MFMA); also emits bf16(h) into Abuf[:,0:128] ----------------
__global__ __launch_bounds__(256) void k_p12(const float* __restrict__ h,
                                             const unsigned short* __restrict__ W12t,
                                             unsigned short* __restrict__ P1,
                                             unsigned short* __restrict__ P2,
                                             unsigned short* __restrict__ Abuf) {
    __shared__ __align__(16) unsigned short As[64 * 128];
    __shared__ __align__(16) unsigned short Bs[256 * 128];
    const int t = threadIdx.x;
    const size_t row0 = (size_t)blockIdx.x * 64;
#pragma unroll
    for (int j = 0; j < 16; ++j) {
        int idx = t + 256 * j;
        int n = idx >> 4, q = idx & 15;
        uint4 wv = *(const uint4*)(W12t + n * 128 + q * 8);
        *(uint4*)((char*)Bs + n * 256 + ((q * 16) ^ ((n & 7) << 4))) = wv;
    }
#pragma unroll
    for (int j = 0; j < 8; ++j) {
        int idx = t + 256 * j;
        int r = idx >> 5, q = idx & 31;
        size_t row = row0 + r;
        uint2 p = {0u, 0u};
        if (row < NNODES) {
            float4 z = ((const float4*)h)[row * 32 + q];
            p.x = f2bf(z.x) | (f2bf(z.y) << 16);
            p.y = f2bf(z.z) | (f2bf(z.w) << 16);
            *(uint2*)(Abuf + row * 640 + q * 4) = p;
        }
        *(uint2*)((char*)As + r * 256 + ((q * 8) ^ ((r & 7) << 4))) = p;
    }
    __syncthreads();
    const int w = t >> 6, lane = t & 63, lrow = lane & 15, lkb = lane >> 4;
    f32x4 acc[16];
#pragma unroll
    for (int i = 0; i < 16; ++i) acc[i] = (f32x4){0.f, 0.f, 0.f, 0.f};
    const char* Abase = (const char*)As + (w * 16 + lrow) * 256;
    const unsigned aswz = (unsigned)(((w * 16 + lrow) & 7) << 4);
#pragma unroll
    for (int kk = 0; kk < 4; ++kk) {
        int kbyte = (kk * 32 + lkb * 8) * 2;
        short8 af = *(const short8*)(Abase + (kbyte ^ aswz));
#pragma unroll
        for (int nt = 0; nt < 16; ++nt) {
            int n = nt * 16 + lrow;
            short8 bf = *(const short8*)((const char*)Bs + n * 256 + (kbyte ^ ((n & 7) << 4)));
            acc[nt] = __builtin_amdgcn_mfma_f32_16x16x32_bf16(af, bf, acc[nt], 0, 0, 0);
        }
    }
#pragma unroll
    for (int half = 0; half < 2; ++half) {
        __syncthreads();
#pragma unroll
        for (int nt = 0; nt < 8; ++nt) {
            int c = nt * 16 + lrow;
#pragma unroll
            for (int i = 0; i < 4; ++i) {
                int lr = w * 16 + lkb * 4 + i;
                *(unsigned short*)((char*)As + lr * 256 + ((c * 2) ^ ((lr & 7) << 4))) =
                    (unsigned short)f2bf(acc[half * 8 + nt][i]);
            }
        }
        __syncthreads();
        unsigned short* dstP = half ? P2 : P1;
#pragma unroll
        for (int j = 0; j < 4; ++j) {
            int idx = t + 256 * j;
            int r = idx >> 4, q = idx & 15;
            size_t row = row0 + r;
            if (row < NNODES) {
                uint4 v = *(const uint4*)((const char*)As + r * 256 + ((q * 16) ^ ((r & 7) << 4)));
                *(uint4*)(dstP + row * 128 + q * 8) = v;
            }
        }
    }
}

// ---------------- G[slotArr[eid]] = bf16(e[eid]@W3 + bpre + P1[src[eid]]) ----------------
// A-fragments loaded DIRECTLY from global e (no LDS staging for A): lane reads
// e[row = w*16+lrow][kk*32+lkb*8 .. +8] as 2x float4, cvt to bf16 in regs.
// LDS: Bs 32K (persistent W3) + As 16K (G-flush transpose only) -> 3 blocks/CU.
__global__ __launch_bounds__(256) void k_gemm_e(const float* __restrict__ e,
                                                const int* __restrict__ src,
                                                const int* __restrict__ slotArr,
                                                const unsigned short* __restrict__ W3t,
                                                const float* __restrict__ bpre,
                                                const unsigned short* __restrict__ P1,
                                                unsigned short* __restrict__ G) {
    __shared__ __align__(16) unsigned short Bs[128 * 128];
    __shared__ __align__(16) unsigned short As[64 * 128];
    __shared__ int Ssl[TPB_E * 64];
    __shared__ int Ssr[TPB_E * 64];
    const int t = threadIdx.x;
    const int tile0 = blockIdx.x * TPB_E;
    const int ntiles = min(TPB_E, 12500 - tile0);

    for (int j = t; j < ntiles * 64; j += 256) {
        int row = tile0 * 64 + j;
        Ssl[j] = slotArr[row];
        Ssr[j] = src[row];
    }
#pragma unroll
    for (int j = 0; j < 8; ++j) {
        int idx = t + 256 * j;
        int n = idx >> 4, qq = idx & 15;
        uint4 wv = *(const uint4*)(W3t + n * 128 + qq * 8);
        *(uint4*)((char*)Bs + n * 256 + ((qq * 16) ^ ((n & 7) << 4))) = wv;
    }

    const int w = t >> 6, lane = t & 63, lrow = lane & 15, lkb = lane >> 4;
    float bpf[8];
#pragma unroll
    for (int nt = 0; nt < 8; ++nt) bpf[nt] = bpre[nt * 16 + lrow];
    // per-lane global base for A-fragments: row (w*16+lrow), k-offset lkb*8 floats
    const float* ebase = e + (size_t)(tile0 * 64 + w * 16 + lrow) * 128 + lkb * 8;

    __syncthreads();   // Bs + meta visible

    for (int ti = 0; ti < ntiles; ++ti) {
        const float* ep = ebase + (size_t)ti * 64 * 128;
        short8 af[4];
#pragma unroll
        for (int kk = 0; kk < 4; ++kk) {
            float4 a0 = *(const float4*)(ep + kk * 32);
            float4 a1 = *(const float4*)(ep + kk * 32 + 4);
            union { short8 s; unsigned u[4]; } cv;
            cv.u[0] = f2bf(a0.x) | (f2bf(a0.y) << 16);
            cv.u[1] = f2bf(a0.z) | (f2bf(a0.w) << 16);
            cv.u[2] = f2bf(a1.x) | (f2bf(a1.y) << 16);
            cv.u[3] = f2bf(a1.z) | (f2bf(a1.w) << 16);
            af[kk] = cv.s;
        }
        f32x4 acc[8];
#pragma unroll
        for (int i = 0; i < 8; ++i) acc[i] = (f32x4){0.f, 0.f, 0.f, 0.f};
#pragma unroll
        for (int kk = 0; kk < 4; ++kk) {
            int kbyte = (kk * 32 + lkb * 8) * 2;
#pragma unroll
            for (int nt = 0; nt < 8; ++nt) {
                int n = nt * 16 + lrow;
                short8 bf = *(const short8*)((const char*)Bs + n * 256 + (kbyte ^ ((n & 7) << 4)));
                acc[nt] = __builtin_amdgcn_mfma_f32_16x16x32_bf16(af[kk], bf, acc[nt], 0, 0, 0);
            }
        }
        __syncthreads();   // (A) prev tile's flush reads of As done
#pragma unroll
        for (int nt = 0; nt < 8; ++nt) {
            int cc = nt * 16 + lrow;
#pragma unroll
            for (int i = 0; i < 4; ++i) {
                int lr = w * 16 + lkb * 4 + i;
                *(unsigned short*)((char*)As + lr * 256 + ((cc * 2) ^ ((lr & 7) << 4))) =
                    (unsigned short)f2bf(acc[nt][i] + bpf[nt]);
            }
        }
        __syncthreads();   // (B) scatter visible
        // flush: add P1 row, scatter-write to G[slot]
#pragma unroll
        for (int j = 0; j < 4; ++j) {
            int idx = t + 256 * j;
            int r = idx >> 4, qq = idx & 15;
            uint4 v = *(const uint4*)((const char*)As + r * 256 + ((qq * 16) ^ ((r & 7) << 4)));
            uint4 pv = *(const uint4*)(P1 + (size_t)Ssr[ti * 64 + r] * 128 + qq * 8);
            float gf[8], pf[8];
            up8(v, gf); up8(pv, pf);
#pragma unroll
            for (int k = 0; k < 8; ++k) gf[k] += pf[k];
            *(uint4*)(G + (size_t)Ssl[ti * 64 + r] * 128 + qq * 8) = pk8(gf);
        }
        // no trailing barrier: next tile's barrier (A) covers flush->scatter ordering
    }
}

// ---------------- segmented reduce: stream G (sorted order); P2 shift at flush ----------------
__global__ __launch_bounds__(256) void k_reduce(const unsigned short* __restrict__ G,
                                                const unsigned short* __restrict__ P2,
                                                const int* __restrict__ basep,
                                                unsigned short* __restrict__ Abuf) {
    const int t = threadIdx.x;
    const int n = blockIdx.x * 4 + (t >> 6);
    const int lane = t & 63, lq = lane >> 4, lc = lane & 15;
    int b0 = basep[n], b1 = basep[n + 1];
    int dg = b1 - b0;
    float s[8], q2[8], mx[8], mn[8];
#pragma unroll
    for (int j = 0; j < 8; ++j) { s[j] = 0.f; q2[j] = 0.f; mx[j] = -3.4e38f; mn[j] = 3.4e38f; }
    for (int sl = b0 + lq; sl < b1; sl += 4) {
        float gf[8];
        up8(*(const uint4*)(G + (size_t)sl * 128 + lc * 8), gf);
#pragma unroll
        for (int j = 0; j < 8; ++j) {
            float m = gf[j];
            s[j] += m; q2[j] = fmaf(m, m, q2[j]);
            mx[j] = fmaxf(mx[j], m); mn[j] = fminf(mn[j], m);
        }
    }
#pragma unroll
    for (int off = 16; off <= 32; off <<= 1) {
#pragma unroll
        for (int j = 0; j < 8; ++j) {
            s[j] += __shfl_xor(s[j], off);
            q2[j] += __shfl_xor(q2[j], off);
            mx[j] = fmaxf(mx[j], __shfl_xor(mx[j], off));
            mn[j] = fminf(mn[j], __shfl_xor(mn[j], off));
        }
    }
    if (lane < 16) {
        float mean[8], sd[8], X[8], N[8];
        if (dg > 0) {
            float ds = (float)dg;
            float p2f[8];
            up8(*(const uint4*)(P2 + (size_t)n * 128 + lc * 8), p2f);
#pragma unroll
            for (int j = 0; j < 8; ++j) {
                float mg = s[j] / ds;
                float v = fmaxf(q2[j] / ds - mg * mg, 0.f);
                sd[j] = sqrtf(v + EPSF);
                mean[j] = mg + p2f[j];
                X[j] = mx[j] + p2f[j];
                N[j] = mn[j] + p2f[j];
            }
        } else {
#pragma unroll
            for (int j = 0; j < 8; ++j) { mean[j] = 0.f; sd[j] = 0.f; X[j] = 0.f; N[j] = 0.f; }
        }
        unsigned short* row = Abuf + (size_t)n * 640 + 128 + lc * 8;
        *(uint4*)(row) = pk8(mean);
        *(uint4*)(row + 128) = pk8(X);
        *(uint4*)(row + 256) = pk8(N);
        *(uint4*)(row + 384) = pk8(sd);
    }
}

// ---------------- out = C0 + amp*C1 + att*C2 + b, *snorm ; C = A[50000,640] @ Bhat[640,384] ----------------
__global__ __launch_bounds__(512) void k_gemm_post(const unsigned short* __restrict__ Abuf,
                                                   const unsigned short* __restrict__ Bhat,
                                                   const float* __restrict__ bpost,
                                                   const float* __restrict__ snorm,
                                                   const int* __restrict__ basep,
                                                   float* __restrict__ out) {
    __shared__ __align__(16) unsigned short As[2][128 * 32];
    __shared__ __align__(16) unsigned short Bs[2][384 * 32];
    __shared__ float sAmp[128], sAtt[128], sSn[128], sBp[128];
    const int t = threadIdx.x;
    const size_t row0 = (size_t)blockIdx.x * 128;
    if (t < 128) {
        size_t nn = row0 + t;
        float a = 0.f, b = 0.f, sn = 0.f;
        if (nn < NNODES) {
            int dgi = basep[nn + 1] - basep[nn];
            a = logf((float)dgi + 1.f) * (1.f / AVGDLOG);
            b = AVGDLOG / logf(fmaxf((float)dgi, 1.f) + 1.f);
            sn = snorm[nn];
        }
        sAmp[t] = a; sAtt[t] = b; sSn[t] = sn; sBp[t] = bpost[t];
    }
    const int arow = t >> 2, ak4 = t & 3;
    auto loadA = [&](int kc, uint4& ra) {
        ra = (uint4){0u, 0u, 0u, 0u};
        if (row0 + arow < NNODES)
            ra = *(const uint4*)(Abuf + (row0 + arow) * 640 + kc * 32 + ak4 * 8);
    };
    auto loadB = [&](int kc, uint4* rb) {
#pragma unroll
        for (int j = 0; j < 3; ++j) {
            int idx = t + 512 * j;
            int n = idx >> 2, k4 = idx & 3;
            rb[j] = *(const uint4*)(Bhat + ((size_t)kc * 384 + n) * 32 + k4 * 8);
        }
    };
    auto storeLDS = [&](int buf, const uint4& ra, const uint4* rb) {
        *(uint4*)((char*)As[buf] + arow * 64 + ((ak4 * 16) ^ ((arow & 3) << 4))) = ra;
#pragma unroll
        for (int j = 0; j < 3; ++j) {
            int idx = t + 512 * j;
            int n = idx >> 2, k4 = idx & 3;
            *(uint4*)((char*)Bs[buf] + n * 64 + ((k4 * 16) ^ ((n & 3) << 4))) = rb[j];
        }
    };
    const int w = t >> 6, wm = w & 1, wn = w >> 1;
    const int lane = t & 63, lrow = lane & 15, lkb = lane >> 4;
    f32x4 acc[4][6];
#pragma unroll
    for (int a = 0; a < 4; ++a)
#pragma unroll
        for (int b = 0; b < 6; ++b) acc[a][b] = (f32x4){0.f, 0.f, 0.f, 0.f};

    uint4 ra, rb[3];
    loadA(0, ra); loadB(0, rb);
    storeLDS(0, ra, rb);
    int cur = 0;
    for (int kc = 0; kc < 20; ++kc) {
        if (kc < 19) { loadA(kc + 1, ra); loadB(kc + 1, rb); }
        __syncthreads();
        short8 af[4];
#pragma unroll
        for (int mi = 0; mi < 4; ++mi) {
            int r = wm * 64 + mi * 16 + lrow;
            af[mi] = *(const short8*)((const char*)As[cur] + r * 64 + ((lkb * 16) ^ ((r & 3) << 4)));
        }
        short8 bfv[6];
#pragma unroll
        for (int g = 0; g < 3; ++g)
#pragma unroll
            for (int j = 0; j < 2; ++j) {
                int nn = g * 128 + wn * 32 + j * 16 + lrow;
                bfv[g * 2 + j] = *(const short8*)((const char*)Bs[cur] + nn * 64 + ((lkb * 16) ^ ((nn & 3) << 4)));
            }
#pragma unroll
        for (int mi = 0; mi < 4; ++mi)
#pragma unroll
            for (int f = 0; f < 6; ++f)
                acc[mi][f] = __builtin_amdgcn_mfma_f32_16x16x32_bf16(af[mi], bfv[f], acc[mi][f], 0, 0, 0);
        if (kc < 19) storeLDS(cur ^ 1, ra, rb);
        cur ^= 1;
    }
#pragma unroll
    for (int mi = 0; mi < 4; ++mi)
#pragma unroll
        for (int j = 0; j < 2; ++j)
#pragma unroll
            for (int i = 0; i < 4; ++i) {
                int r = wm * 64 + mi * 16 + lkb * 4 + i;
                size_t grow = row0 + r;
                if (grow < NNODES) {
                    int c = wn * 32 + j * 16 + lrow;
                    float v = acc[mi][j][i] + sAmp[r] * acc[mi][2 + j][i] + sAtt[r] * acc[mi][4 + j][i] + sBp[c];
                    out[grow * 128 + c] = v * sSn[r];
                }
            }
}

extern "C" void kernel_launch(void* const* d_in, const int* in_sizes, int n_in,
                              void* d_out, int out_size, void* d_ws, size_t ws_size,
                              hipStream_t stream) {
    const float* h = (const float*)d_in[0];
    const float* e = (const float*)d_in[1];
    const float* snorm = (const float*)d_in[2];
    const int* src = (const int*)d_in[3];
    const int* dst = (const int*)d_in[4];
    const float* Wpre = (const float*)d_in[5];
    const float* bpre = (const float*)d_in[6];
    const float* Wpost = (const float*)d_in[7];
    const float* bpost = (const float*)d_in[8];
    float* out = (float*)d_out;

    char* p = (char*)d_ws;
    auto alloc = [&](size_t bytes) { char* r = p; p += (bytes + 255) & ~(size_t)255; return r; };
    unsigned short* P1 = (unsigned short*)alloc((size_t)NNODES * 128 * 2);
    unsigned short* P2 = (unsigned short*)alloc((size_t)NNODES * 128 * 2);
    unsigned short* Abuf = (unsigned short*)alloc((size_t)NNODES * 640 * 2);
    unsigned short* G = (unsigned short*)alloc((size_t)NEDGES * 128 * 2);
    unsigned short* W3t = (unsigned short*)alloc(128 * 128 * 2);
    unsigned short* W12t = (unsigned short*)alloc(256 * 128 * 2);
    unsigned short* Bhat = (unsigned short*)alloc((size_t)640 * 384 * 2);
    unsigned* deg = (unsigned*)alloc((size_t)NNODES * 4);
    int* basep = (int*)alloc((size_t)(NNODES + 1) * 4);
    int* cursor = (int*)alloc((size_t)NNODES * 4);
    int* slotArr = (int*)alloc((size_t)NEDGES * 4);
    int* bsum = (int*)alloc((size_t)NSCAN * 4);
    int* boff = (int*)alloc((size_t)NSCAN * 4);

    k_zero<<<(NNODES + 255) / 256, 256, 0, stream>>>(deg);
    k_count<<<(NEDGES + 255) / 256, 256, 0, stream>>>(dst, deg);
    k_scanA<<<NSCAN, 256, 0, stream>>>(deg, bsum);
    k_scanB<<<1, 64, 0, stream>>>(bsum, boff, basep);
    k_scanC<<<NSCAN, 256, 0, stream>>>(deg, boff, basep, cursor);
    k_scatter<<<(NEDGES + 255) / 256, 256, 0, stream>>>(dst, cursor, slotArr);
    k_convW<<<(640 * 384 + 255) / 256, 256, 0, stream>>>(Wpre, Wpost, W3t, W12t, Bhat);
    k_p12<<<(NNODES + 63) / 64, 256, 0, stream>>>(h, W12t, P1, P2, Abuf);
    k_gemm_e<<<(12500 + TPB_E - 1) / TPB_E, 256, 0, stream>>>(e, src, slotArr, W3t, bpre, P1, G);
    k_reduce<<<NNODES / 4, 256, 0, stream>>>(G, P2, basep, Abuf);
    k_gemm_post<<<(NNODES + 127) / 128, 512, 0, stream>>>(Abuf, Bhat, bpost, snorm, basep, out);
}

// Round 15
// 450.371 us; speedup vs baseline: 1.2429x; 1.0764x over previous
//
#include <hip/hip_runtime.h>
#include <math.h>

#define NNODES 50000
#define NEDGES 800000
#define AVGDLOG 2.833f
#define EPSF 1e-5f
#define TPB_E 8
#define NSCAN 49  // ceil(50000/1024)

typedef __attribute__((ext_vector_type(8))) short short8;
typedef __attribute__((ext_vector_type(4))) float f32x4;

__device__ __forceinline__ unsigned f2bf(float x) {
    unsigned u = __float_as_uint(x);
    return (u + 0x7FFFu + ((u >> 16) & 1u)) >> 16;
}
__device__ __forceinline__ float bf2f(unsigned lo16) {
    return __uint_as_float(lo16 << 16);
}
__device__ __forceinline__ void up8(uint4 v, float* f) {
    f[0] = bf2f(v.x & 0xffffu); f[1] = bf2f(v.x >> 16);
    f[2] = bf2f(v.y & 0xffffu); f[3] = bf2f(v.y >> 16);
    f[4] = bf2f(v.z & 0xffffu); f[5] = bf2f(v.z >> 16);
    f[6] = bf2f(v.w & 0xffffu); f[7] = bf2f(v.w >> 16);
}
__device__ __forceinline__ uint4 pk8(const float* f) {
    uint4 v;
    v.x = f2bf(f[0]) | (f2bf(f[1]) << 16);
    v.y = f2bf(f[2]) | (f2bf(f[3]) << 16);
    v.z = f2bf(f[4]) | (f2bf(f[5]) << 16);
    v.w = f2bf(f[6]) | (f2bf(f[7]) << 16);
    return v;
}

// ---------------- CSR ----------------
__global__ void k_zero(unsigned* __restrict__ deg) {
    int i = blockIdx.x * 256 + threadIdx.x;
    if (i < NNODES) deg[i] = 0u;
}
__global__ void k_count(const int* __restrict__ dst, unsigned* __restrict__ deg) {
    int i = blockIdx.x * 256 + threadIdx.x;
    if (i < NEDGES) atomicAdd(&deg[dst[i]], 1u);
}
__global__ void k_scanA(const unsigned* __restrict__ deg, int* __restrict__ bsum) {
    __shared__ int wsum[4];
    const int t = threadIdx.x, b = blockIdx.x;
    int i = b * 1024 + t * 4;
    int s = 0;
    if (i + 4 <= NNODES) {
        int4 v = *(const int4*)(deg + i);
        s = v.x + v.y + v.z + v.w;
    } else {
        for (int k = 0; k < 4; ++k) if (i + k < NNODES) s += (int)deg[i + k];
    }
#pragma unroll
    for (int off = 1; off < 64; off <<= 1) s += __shfl_xor(s, off);
    if ((t & 63) == 0) wsum[t >> 6] = s;
    __syncthreads();
    if (t == 0) bsum[b] = wsum[0] + wsum[1] + wsum[2] + wsum[3];
}
__global__ void k_scanB(const int* __restrict__ bsum, int* __restrict__ boff,
                        int* __restrict__ basep) {
    if (threadIdx.x == 0) {
        int run = 0;
        for (int b = 0; b < NSCAN; ++b) { boff[b] = run; run += bsum[b]; }
        basep[NNODES] = run;
    }
}
__global__ void k_scanC(const unsigned* __restrict__ deg, const int* __restrict__ boff,
                        int* __restrict__ basep, int* __restrict__ cursor) {
    __shared__ int ps[256];
    const int t = threadIdx.x, b = blockIdx.x;
    int i = b * 1024 + t * 4;
    int v0 = 0, v1 = 0, v2 = 0, v3 = 0;
    if (i + 4 <= NNODES) {
        int4 v = *(const int4*)(deg + i);
        v0 = v.x; v1 = v.y; v2 = v.z; v3 = v.w;
    } else {
        if (i < NNODES) v0 = (int)deg[i];
        if (i + 1 < NNODES) v1 = (int)deg[i + 1];
        if (i + 2 < NNODES) v2 = (int)deg[i + 2];
        if (i + 3 < NNODES) v3 = (int)deg[i + 3];
    }
    int ts = v0 + v1 + v2 + v3;
    ps[t] = ts;
    __syncthreads();
    for (int off = 1; off < 256; off <<= 1) {
        int x = (t >= off) ? ps[t - off] : 0;
        __syncthreads();
        ps[t] += x;
        __syncthreads();
    }
    int excl = ps[t] - ts + boff[b];
    if (i < NNODES) { basep[i] = excl; cursor[i] = excl; }
    if (i + 1 < NNODES) { basep[i + 1] = excl + v0; cursor[i + 1] = excl + v0; }
    if (i + 2 < NNODES) { basep[i + 2] = excl + v0 + v1; cursor[i + 2] = excl + v0 + v1; }
    if (i + 3 < NNODES) { basep[i + 3] = excl + v0 + v1 + v2; cursor[i + 3] = excl + v0 + v1 + v2; }
}
__global__ void k_scatter(const int* __restrict__ dst, int* __restrict__ cursor,
                          int* __restrict__ slotArr) {
    int i = blockIdx.x * 256 + threadIdx.x;
    if (i < NEDGES) {
        int d = dst[i];
        slotArr[i] = atomicAdd(&cursor[d], 1);
    }
}

// ---------------- weight prep ----------------
__global__ void k_convW(const float* __restrict__ Wpre, const float* __restrict__ Wpost,
                        unsigned short* __restrict__ W3t, unsigned short* __restrict__ W12t,
                        unsigned short* __restrict__ Bhat) {
    int i = blockIdx.x * 256 + threadIdx.x;
    if (i < 128 * 128) {
        int n = i & 127, k = i >> 7;
        W3t[n * 128 + k] = (unsigned short)f2bf(Wpre[(256 + k) * 128 + n]);
    }
    if (i < 256 * 128) {
        int n = i >> 7, k = i & 127;
        float v = (n < 128) ? Wpre[k * 128 + n] : Wpre[(128 + k) * 128 + (n - 128)];
        W12t[n * 128 + k] = (unsigned short)f2bf(v);
    }
    if (i < 640 * 384) {
        int kc = i / (384 * 32);
        int rem = i % (384 * 32);
        int n = rem >> 5, kk = rem & 31;
        int k = kc * 32 + kk, c = n & 127, g = n >> 7;
        float v;
        if (g == 0) v = Wpost[k * 128 + c];
        else if (g == 1) v = (k < 128) ? 0.f : Wpost[(512 + k) * 128 + c];
        else v = (k < 128) ? 0.f : Wpost[(1024 + k) * 128 + c];
        Bhat[i] = (unsigned short)f2bf(v);
    }
}

// ---------------- P12 = h @ [W1|W2] (MFMA); also emits bf16(h) into Abuf[:,0:128] ----------------
__global__ __launch_bounds__(256) void k_p12(const float* __restrict__ h,
                                             const unsigned short* __restrict__ W12t,
                                             unsigned short* __restrict__ P1,
                                             unsigned short* __restrict__ P2,
                                             unsigned short* __restrict__ Abuf) {
    __shared__ __align__(16) unsigned short As[64 * 128];
    __shared__ __align__(16) unsigned short Bs[256 * 128];
    const int t = threadIdx.x;
    const size_t row0 = (size_t)blockIdx.x * 64;
#pragma unroll
    for (int j = 0; j < 16; ++j) {
        int idx = t + 256 * j;
        int n = idx >> 4, q = idx & 15;
        uint4 wv = *(const uint4*)(W12t + n * 128 + q * 8);
        *(uint4*)((char*)Bs + n * 256 + ((q * 16) ^ ((n & 7) << 4))) = wv;
    }
#pragma unroll
    for (int j = 0; j < 8; ++j) {
        int idx = t + 256 * j;
        int r = idx >> 5, q = idx & 31;
        size_t row = row0 + r;
        uint2 p = {0u, 0u};
        if (row < NNODES) {
            float4 z = ((const float4*)h)[row * 32 + q];
            p.x = f2bf(z.x) | (f2bf(z.y) << 16);
            p.y = f2bf(z.z) | (f2bf(z.w) << 16);
            *(uint2*)(Abuf + row * 640 + q * 4) = p;
        }
        *(uint2*)((char*)As + r * 256 + ((q * 8) ^ ((r & 7) << 4))) = p;
    }
    __syncthreads();
    const int w = t >> 6, lane = t & 63, lrow = lane & 15, lkb = lane >> 4;
    f32x4 acc[16];
#pragma unroll
    for (int i = 0; i < 16; ++i) acc[i] = (f32x4){0.f, 0.f, 0.f, 0.f};
    const char* Abase = (const char*)As + (w * 16 + lrow) * 256;
    const unsigned aswz = (unsigned)(((w * 16 + lrow) & 7) << 4);
#pragma unroll
    for (int kk = 0; kk < 4; ++kk) {
        int kbyte = (kk * 32 + lkb * 8) * 2;
        short8 af = *(const short8*)(Abase + (kbyte ^ aswz));
#pragma unroll
        for (int nt = 0; nt < 16; ++nt) {
            int n = nt * 16 + lrow;
            short8 bf = *(const short8*)((const char*)Bs + n * 256 + (kbyte ^ ((n & 7) << 4)));
            acc[nt] = __builtin_amdgcn_mfma_f32_16x16x32_bf16(af, bf, acc[nt], 0, 0, 0);
        }
    }
#pragma unroll
    for (int half = 0; half < 2; ++half) {
        __syncthreads();
#pragma unroll
        for (int nt = 0; nt < 8; ++nt) {
            int c = nt * 16 + lrow;
#pragma unroll
            for (int i = 0; i < 4; ++i) {
                int lr = w * 16 + lkb * 4 + i;
                *(unsigned short*)((char*)As + lr * 256 + ((c * 2) ^ ((lr & 7) << 4))) =
                    (unsigned short)f2bf(acc[half * 8 + nt][i]);
            }
        }
        __syncthreads();
        unsigned short* dstP = half ? P2 : P1;
#pragma unroll
        for (int j = 0; j < 4; ++j) {
            int idx = t + 256 * j;
            int r = idx >> 4, q = idx & 15;
            size_t row = row0 + r;
            if (row < NNODES) {
                uint4 v = *(const uint4*)((const char*)As + r * 256 + ((q * 16) ^ ((r & 7) << 4)));
                *(uint4*)(dstP + row * 128 + q * 8) = v;
            }
        }
    }
}

// ---------------- G[slotArr[eid]] = bf16(e[eid]@W3 + bpre + P1[src[eid]])  (round-9 exact) ----------------
__global__ __launch_bounds__(256) void k_gemm_e(const float* __restrict__ e,
                                                const int* __restrict__ src,
                                                const int* __restrict__ slotArr,
                                                const unsigned short* __restrict__ W3t,
                                                const float* __restrict__ bpre,
                                                const unsigned short* __restrict__ P1,
                                                unsigned short* __restrict__ G) {
    __shared__ __align__(16) unsigned short Bs[128 * 128];   // persistent W3
    __shared__ __align__(16) unsigned short As[2][64 * 128]; // double-buffered A
    __shared__ int Ssl[TPB_E * 64];
    __shared__ int Ssr[TPB_E * 64];
    const int t = threadIdx.x;
    const int tile0 = blockIdx.x * TPB_E;
    const int ntiles = min(TPB_E, 12500 - tile0);

    for (int j = t; j < ntiles * 64; j += 256) {
        int row = tile0 * 64 + j;
        Ssl[j] = slotArr[row];
        Ssr[j] = src[row];
    }

    const int q = t & 31, r5 = t >> 5;
    auto loadE = [&](int ti, float4* ra) {
        const float4* ep = (const float4*)e + (size_t)(tile0 + ti) * 2048;
#pragma unroll
        for (int j = 0; j < 8; ++j)
            ra[j] = ep[(r5 + 8 * j) * 32 + q];   // fully linear, coalesced
    };
    auto storeA = [&](int buf, const float4* ra) {
#pragma unroll
        for (int j = 0; j < 8; ++j) {
            int r = r5 + 8 * j;
            uint2 pv;
            pv.x = f2bf(ra[j].x) | (f2bf(ra[j].y) << 16);
            pv.y = f2bf(ra[j].z) | (f2bf(ra[j].w) << 16);
            *(uint2*)((char*)As[buf] + r * 256 + ((q * 8) ^ ((r & 7) << 4))) = pv;
        }
    };

    float4 ra[8];
    loadE(0, ra);
#pragma unroll
    for (int j = 0; j < 8; ++j) {
        int idx = t + 256 * j;
        int n = idx >> 4, qq = idx & 15;
        uint4 wv = *(const uint4*)(W3t + n * 128 + qq * 8);
        *(uint4*)((char*)Bs + n * 256 + ((qq * 16) ^ ((n & 7) << 4))) = wv;
    }
    storeA(0, ra);
    if (ntiles > 1) loadE(1, ra);
    __syncthreads();

    const int w = t >> 6, lane = t & 63, lrow = lane & 15, lkb = lane >> 4;
    float bpf[8];
#pragma unroll
    for (int nt = 0; nt < 8; ++nt) bpf[nt] = bpre[nt * 16 + lrow];

    for (int ti = 0; ti < ntiles; ++ti) {
        const int c = ti & 1;
        f32x4 acc[8];
#pragma unroll
        for (int i = 0; i < 8; ++i) acc[i] = (f32x4){0.f, 0.f, 0.f, 0.f};
        const char* Ab = (const char*)As[c] + (w * 16 + lrow) * 256;
        const unsigned aswz = (unsigned)(((w * 16 + lrow) & 7) << 4);
#pragma unroll
        for (int kk = 0; kk < 4; ++kk) {
            int kbyte = (kk * 32 + lkb * 8) * 2;
            short8 af = *(const short8*)(Ab + (kbyte ^ aswz));
#pragma unroll
            for (int nt = 0; nt < 8; ++nt) {
                int n = nt * 16 + lrow;
                short8 bf = *(const short8*)((const char*)Bs + n * 256 + (kbyte ^ ((n & 7) << 4)));
                acc[nt] = __builtin_amdgcn_mfma_f32_16x16x32_bf16(af, bf, acc[nt], 0, 0, 0);
            }
        }
        __syncthreads();  // MFMA reads of As[c] + prev flush reads drained
#pragma unroll
        for (int nt = 0; nt < 8; ++nt) {
            int cc = nt * 16 + lrow;
#pragma unroll
            for (int i = 0; i < 4; ++i) {
                int lr = w * 16 + lkb * 4 + i;
                *(unsigned short*)((char*)As[c] + lr * 256 + ((cc * 2) ^ ((lr & 7) << 4))) =
                    (unsigned short)f2bf(acc[nt][i] + bpf[nt]);
            }
        }
        if (ti + 1 < ntiles) {
            storeA(c ^ 1, ra);
            if (ti + 2 < ntiles) loadE(ti + 2, ra);
        }
        __syncthreads();  // scatter + next-tile stage visible
        // flush: add P1 row, scatter-write to G[slot]
#pragma unroll
        for (int j = 0; j < 4; ++j) {
            int idx = t + 256 * j;
            int r = idx >> 4, qq = idx & 15;
            uint4 v = *(const uint4*)((const char*)As[c] + r * 256 + ((qq * 16) ^ ((r & 7) << 4)));
            uint4 pv = *(const uint4*)(P1 + (size_t)Ssr[ti * 64 + r] * 128 + qq * 8);
            float gf[8], pf[8];
            up8(v, gf); up8(pv, pf);
#pragma unroll
            for (int k = 0; k < 8; ++k) gf[k] += pf[k];
            *(uint4*)(G + (size_t)Ssl[ti * 64 + r] * 128 + qq * 8) = pk8(gf);
        }
    }
}

// ---------------- segmented reduce: stream G (sorted order); P2 shift at flush ----------------
__global__ __launch_bounds__(256) void k_reduce(const unsigned short* __restrict__ G,
                                                const unsigned short* __restrict__ P2,
                                                const int* __restrict__ basep,
                                                unsigned short* __restrict__ Abuf) {
    const int t = threadIdx.x;
    const int n = blockIdx.x * 4 + (t >> 6);
    const int lane = t & 63, lq = lane >> 4, lc = lane & 15;
    int b0 = basep[n], b1 = basep[n + 1];
    int dg = b1 - b0;
    float s[8], q2[8], mx[8], mn[8];
#pragma unroll
    for (int j = 0; j < 8; ++j) { s[j] = 0.f; q2[j] = 0.f; mx[j] = -3.4e38f; mn[j] = 3.4e38f; }
    for (int sl = b0 + lq; sl < b1; sl += 4) {
        float gf[8];
        up8(*(const uint4*)(G + (size_t)sl * 128 + lc * 8), gf);
#pragma unroll
        for (int j = 0; j < 8; ++j) {
            float m = gf[j];
            s[j] += m; q2[j] = fmaf(m, m, q2[j]);
            mx[j] = fmaxf(mx[j], m); mn[j] = fminf(mn[j], m);
        }
    }
#pragma unroll
    for (int off = 16; off <= 32; off <<= 1) {
#pragma unroll
        for (int j = 0; j < 8; ++j) {
            s[j] += __shfl_xor(s[j], off);
            q2[j] += __shfl_xor(q2[j], off);
            mx[j] = fmaxf(mx[j], __shfl_xor(mx[j], off));
            mn[j] = fminf(mn[j], __shfl_xor(mn[j], off));
        }
    }
    if (lane < 16) {
        float mean[8], sd[8], X[8], N[8];
        if (dg > 0) {
            float ds = (float)dg;
            float p2f[8];
            up8(*(const uint4*)(P2 + (size_t)n * 128 + lc * 8), p2f);
#pragma unroll
            for (int j = 0; j < 8; ++j) {
                float mg = s[j] / ds;
                float v = fmaxf(q2[j] / ds - mg * mg, 0.f);
                sd[j] = sqrtf(v + EPSF);
                mean[j] = mg + p2f[j];
                X[j] = mx[j] + p2f[j];
                N[j] = mn[j] + p2f[j];
            }
        } else {
#pragma unroll
            for (int j = 0; j < 8; ++j) { mean[j] = 0.f; sd[j] = 0.f; X[j] = 0.f; N[j] = 0.f; }
        }
        unsigned short* row = Abuf + (size_t)n * 640 + 128 + lc * 8;
        *(uint4*)(row) = pk8(mean);
        *(uint4*)(row + 128) = pk8(X);
        *(uint4*)(row + 256) = pk8(N);
        *(uint4*)(row + 384) = pk8(sd);
    }
}

// ---------------- out = C0 + amp*C1 + att*C2 + b, *snorm ; C = A[50000,640] @ Bhat[640,384] ----------------
__global__ __launch_bounds__(512) void k_gemm_post(const unsigned short* __restrict__ Abuf,
                                                   const unsigned short* __restrict__ Bhat,
                                                   const float* __restrict__ bpost,
                                                   const float* __restrict__ snorm,
                                                   const int* __restrict__ basep,
                                                   float* __restrict__ out) {
    __shared__ __align__(16) unsigned short As[2][128 * 32];
    __shared__ __align__(16) unsigned short Bs[2][384 * 32];
    __shared__ float sAmp[128], sAtt[128], sSn[128], sBp[128];
    const int t = threadIdx.x;
    const size_t row0 = (size_t)blockIdx.x * 128;
    if (t < 128) {
        size_t nn = row0 + t;
        float a = 0.f, b = 0.f, sn = 0.f;
        if (nn < NNODES) {
            int dgi = basep[nn + 1] - basep[nn];
            a = logf((float)dgi + 1.f) * (1.f / AVGDLOG);
            b = AVGDLOG / logf(fmaxf((float)dgi, 1.f) + 1.f);
            sn = snorm[nn];
        }
        sAmp[t] = a; sAtt[t] = b; sSn[t] = sn; sBp[t] = bpost[t];
    }
    const int arow = t >> 2, ak4 = t & 3;
    auto loadA = [&](int kc, uint4& ra) {
        ra = (uint4){0u, 0u, 0u, 0u};
        if (row0 + arow < NNODES)
            ra = *(const uint4*)(Abuf + (row0 + arow) * 640 + kc * 32 + ak4 * 8);
    };
    auto loadB = [&](int kc, uint4* rb) {
#pragma unroll
        for (int j = 0; j < 3; ++j) {
            int idx = t + 512 * j;
            int n = idx >> 2, k4 = idx & 3;
            rb[j] = *(const uint4*)(Bhat + ((size_t)kc * 384 + n) * 32 + k4 * 8);
        }
    };
    auto storeLDS = [&](int buf, const uint4& ra, const uint4* rb) {
        *(uint4*)((char*)As[buf] + arow * 64 + ((ak4 * 16) ^ ((arow & 3) << 4))) = ra;
#pragma unroll
        for (int j = 0; j < 3; ++j) {
            int idx = t + 512 * j;
            int n = idx >> 2, k4 = idx & 3;
            *(uint4*)((char*)Bs[buf] + n * 64 + ((k4 * 16) ^ ((n & 3) << 4))) = rb[j];
        }
    };
    const int w = t >> 6, wm = w & 1, wn = w >> 1;
    const int lane = t & 63, lrow = lane & 15, lkb = lane >> 4;
    f32x4 acc[4][6];
#pragma unroll
    for (int a = 0; a < 4; ++a)
#pragma unroll
        for (int b = 0; b < 6; ++b) acc[a][b] = (f32x4){0.f, 0.f, 0.f, 0.f};

    uint4 ra, rb[3];
    loadA(0, ra); loadB(0, rb);
    storeLDS(0, ra, rb);
    int cur = 0;
    for (int kc = 0; kc < 20; ++kc) {
        if (kc < 19) { loadA(kc + 1, ra); loadB(kc + 1, rb); }
        __syncthreads();
        short8 af[4];
#pragma unroll
        for (int mi = 0; mi < 4; ++mi) {
            int r = wm * 64 + mi * 16 + lrow;
            af[mi] = *(const short8*)((const char*)As[cur] + r * 64 + ((lkb * 16) ^ ((r & 3) << 4)));
        }
        short8 bfv[6];
#pragma unroll
        for (int g = 0; g < 3; ++g)
#pragma unroll
            for (int j = 0; j < 2; ++j) {
                int nn = g * 128 + wn * 32 + j * 16 + lrow;
                bfv[g * 2 + j] = *(const short8*)((const char*)Bs[cur] + nn * 64 + ((lkb * 16) ^ ((nn & 3) << 4)));
            }
#pragma unroll
        for (int mi = 0; mi < 4; ++mi)
#pragma unroll
            for (int f = 0; f < 6; ++f)
                acc[mi][f] = __builtin_amdgcn_mfma_f32_16x16x32_bf16(af[mi], bfv[f], acc[mi][f], 0, 0, 0);
        if (kc < 19) storeLDS(cur ^ 1, ra, rb);
        cur ^= 1;
    }
#pragma unroll
    for (int mi = 0; mi < 4; ++mi)
#pragma unroll
        for (int j = 0; j < 2; ++j)
#pragma unroll
            for (int i = 0; i < 4; ++i) {
                int r = wm * 64 + mi * 16 + lkb * 4 + i;
                size_t grow = row0 + r;
                if (grow < NNODES) {
                    int c = wn * 32 + j * 16 + lrow;
                    float v = acc[mi][j][i] + sAmp[r] * acc[mi][2 + j][i] + sAtt[r] * acc[mi][4 + j][i] + sBp[c];
                    out[grow * 128 + c] = v * sSn[r];
                }
            }
}

extern "C" void kernel_launch(void* const* d_in, const int* in_sizes, int n_in,
                              void* d_out, int out_size, void* d_ws, size_t ws_size,
                              hipStream_t stream) {
    const float* h = (const float*)d_in[0];
    const float* e = (const float*)d_in[1];
    const float* snorm = (const float*)d_in[2];
    const int* src = (const int*)d_in[3];
    const int* dst = (const int*)d_in[4];
    const float* Wpre = (const float*)d_in[5];
    const float* bpre = (const float*)d_in[6];
    const float* Wpost = (const float*)d_in[7];
    const float* bpost = (const float*)d_in[8];
    float* out = (float*)d_out;

    char* p = (char*)d_ws;
    auto alloc = [&](size_t bytes) { char* r = p; p += (bytes + 255) & ~(size_t)255; return r; };
    unsigned short* P1 = (unsigned short*)alloc((size_t)NNODES * 128 * 2);
    unsigned short* P2 = (unsigned short*)alloc((size_t)NNODES * 128 * 2);
    unsigned short* Abuf = (unsigned short*)alloc((size_t)NNODES * 640 * 2);
    unsigned short* G = (unsigned short*)alloc((size_t)NEDGES * 128 * 2);
    unsigned short* W3t = (unsigned short*)alloc(128 * 128 * 2);
    unsigned short* W12t = (unsigned short*)alloc(256 * 128 * 2);
    unsigned short* Bhat = (unsigned short*)alloc((size_t)640 * 384 * 2);
    unsigned* deg = (unsigned*)alloc((size_t)NNODES * 4);
    int* basep = (int*)alloc((size_t)(NNODES + 1) * 4);
    int* cursor = (int*)alloc((size_t)NNODES * 4);
    int* slotArr = (int*)alloc((size_t)NEDGES * 4);
    int* bsum = (int*)alloc((size_t)NSCAN * 4);
    int* boff = (int*)alloc((size_t)NSCAN * 4);

    k_zero<<<(NNODES + 255) / 256, 256, 0, stream>>>(deg);
    k_count<<<(NEDGES + 255) / 256, 256, 0, stream>>>(dst, deg);
    k_scanA<<<NSCAN, 256, 0, stream>>>(deg, bsum);
    k_scanB<<<1, 64, 0, stream>>>(bsum, boff, basep);
    k_scanC<<<NSCAN, 256, 0, stream>>>(deg, boff, basep, cursor);
    k_scatter<<<(NEDGES + 255) / 256, 256, 0, stream>>>(dst, cursor, slotArr);
    k_convW<<<(640 * 384 + 255) / 256, 256, 0, stream>>>(Wpre, Wpost, W3t, W12t, Bhat);
    k_p12<<<(NNODES + 63) / 64, 256, 0, stream>>>(h, W12t, P1, P2, Abuf);
    k_gemm_e<<<(12500 + TPB_E - 1) / TPB_E, 256, 0, stream>>>(e, src, slotArr, W3t, bpre, P1, G);
    k_reduce<<<NNODES / 4, 256, 0, stream>>>(G, P2, basep, Abuf);
    k_gemm_post<<<(NNODES + 127) / 128, 512, 0, stream>>>(Abuf, Bhat, bpost, snorm, basep, out);
}